// Round 1
// baseline (581.814 us; speedup 1.0000x reference)
//
#include <hip/hip_runtime.h>
#include <hip/hip_bf16.h>

// ---------------------------------------------------------------------------
// Kernel A: fused dense1+dense2.  h2 = relu(relu(x@w1+b1)@w2+b2)
// (unchanged from previous round — isolating kernel-B changes)
// ---------------------------------------------------------------------------
__launch_bounds__(256)
__global__ void fused_mlp12(const float* __restrict__ x,
                            const float* __restrict__ w1, const float* __restrict__ b1,
                            const float* __restrict__ w2, const float* __restrict__ b2,
                            float* __restrict__ h2out) {
  constexpr int BM = 64, KC = 20, BMP = 68;  // BMP*4B = 272B, 16B-aligned rows
  __shared__ float At[KC * BMP];    // 5.4 KB  staging: x^T chunk [k][r]
  __shared__ float Ws[KC * 128];    // 10.2 KB staging: weight chunk [k][c], cols padded
  __shared__ float h1T[100 * BMP];  // 27.2 KB h1 transposed [k][r]

  const int t = threadIdx.x;
  const int tx = t & 31;
  const int ty = t >> 5;
  const int rowBase = blockIdx.x * BM;

  float acc[8][4];
#pragma unroll
  for (int i = 0; i < 8; i++)
#pragma unroll
    for (int j = 0; j < 4; j++) acc[i][j] = 0.0f;

  // ---- GEMM 1: x(64x200) @ w1(200x100) ----
  for (int kc = 0; kc < 200; kc += KC) {
#pragma unroll
    for (int i = t; i < BM * KC; i += 256) {
      int r = i / KC, k = i - r * KC;
      At[k * BMP + r] = x[(rowBase + r) * 200 + kc + k];
    }
#pragma unroll
    for (int i = t; i < KC * 128; i += 256) {
      int k = i >> 7, c = i & 127;
      Ws[i] = (c < 100) ? w1[(kc + k) * 100 + c] : 0.0f;
    }
    __syncthreads();
#pragma unroll
    for (int k = 0; k < KC; k++) {
      float a[8], b[4];
      *(float4*)&a[0] = *(const float4*)&At[k * BMP + ty * 8];
      *(float4*)&a[4] = *(const float4*)&At[k * BMP + ty * 8 + 4];
      *(float4*)&b[0] = *(const float4*)&Ws[k * 128 + tx * 4];
#pragma unroll
      for (int i = 0; i < 8; i++)
#pragma unroll
        for (int j = 0; j < 4; j++) acc[i][j] += a[i] * b[j];
    }
    __syncthreads();
  }

  // h1 (bias+relu) -> LDS transposed [k][r]
  if (tx < 25) {
#pragma unroll
    for (int i = 0; i < 8; i++) {
      const int r = ty * 8 + i;
#pragma unroll
      for (int j = 0; j < 4; j++) {
        const int c = tx * 4 + j;
        h1T[c * BMP + r] = fmaxf(acc[i][j] + b1[c], 0.0f);
      }
    }
  }
  __syncthreads();

  // ---- GEMM 2: h1(64x100) @ w2(100x100) ----
#pragma unroll
  for (int i = 0; i < 8; i++)
#pragma unroll
    for (int j = 0; j < 4; j++) acc[i][j] = 0.0f;

  for (int kc = 0; kc < 100; kc += KC) {
#pragma unroll
    for (int i = t; i < KC * 128; i += 256) {
      int k = i >> 7, c = i & 127;
      Ws[i] = (c < 100) ? w2[(kc + k) * 100 + c] : 0.0f;
    }
    __syncthreads();
#pragma unroll
    for (int k = 0; k < KC; k++) {
      float a[8], b[4];
      *(float4*)&a[0] = *(const float4*)&h1T[(kc + k) * BMP + ty * 8];
      *(float4*)&a[4] = *(const float4*)&h1T[(kc + k) * BMP + ty * 8 + 4];
      *(float4*)&b[0] = *(const float4*)&Ws[k * 128 + tx * 4];
#pragma unroll
      for (int i = 0; i < 8; i++)
#pragma unroll
        for (int j = 0; j < 4; j++) acc[i][j] += a[i] * b[j];
    }
    __syncthreads();
  }

  if (tx < 25) {
#pragma unroll
    for (int i = 0; i < 8; i++) {
      const int r = rowBase + ty * 8 + i;
      float4 v;
      v.x = fmaxf(acc[i][0] + b2[tx * 4 + 0], 0.0f);
      v.y = fmaxf(acc[i][1] + b2[tx * 4 + 1], 0.0f);
      v.z = fmaxf(acc[i][2] + b2[tx * 4 + 2], 0.0f);
      v.w = fmaxf(acc[i][3] + b2[tx * 4 + 3], 0.0f);
      *(float4*)&h2out[r * 100 + tx * 4] = v;
    }
  }
}

// ---------------------------------------------------------------------------
// Kernel B: fused logits-GEMM + SampleConcrete + head.
// Changes this round:
//  1) LDS union: phase-1 staging (At 5.4KB + Ws 20.5KB) aliased under the
//     logits tile lg (51.2KB). LDS 77.3KB -> 51.2KB => 3 blocks/CU (24 waves).
//  2) Factorized gumbel-softmax: softmax(2g+2lg) with g=-ln(-ln u) equals
//     el_d * (log2 u)^-2 / sum, where el_d = exp(2*(lg_d - lgmax)) is computed
//     ONCE per row. Per sample: 1 log + 1 rcp per element, NO max-reduce.
//     (ln^2(2) factor cancels in the softmax.)
//     Bounds: el<=1, (log2 u)^-2 <= 1.4e14, sum <= 2.7e16 — no overflow; the
//     row-max element has el=1, r>=1/529 — sum>0 always.
//  3) uu[10][4] register batch replaced by 2-deep double buffer (TLP from 3
//     blocks/CU now hides HBM latency); __launch_bounds__(512,6) caps VGPR~80.
// ---------------------------------------------------------------------------
__launch_bounds__(512, 6)
__global__ void fused_logits_concrete(const float* __restrict__ x,
                                      const float* __restrict__ uniform,
                                      const float* __restrict__ h2,
                                      const float* __restrict__ wl, const float* __restrict__ bl,
                                      const float* __restrict__ wo, const float* __restrict__ bo,
                                      float* __restrict__ out, int B) {
  constexpr int BM = 64, KC = 20, BMP = 68;
  constexpr float EPS = 1.1920929e-07f;
  // 51.2 KB total: staging (At 1360 + Ws 5120 floats = 6480) aliases lg[12800].
  __shared__ float smem[BM * 200];
  float* const At = smem;             // [KC][BMP]   (phase 1 only)
  float* const Ws = smem + KC * BMP;  // [KC][256]   (phase 1 only)
  float* const lg = smem;             // [BM][200]   (written after last GEMM sync)

  const int t = threadIdx.x;
  const int rowBase = blockIdx.x * BM;

  // ---- Phase 1: logits = h2(64x100) @ wl(100x200) + bl ----
  {
    const int tx = t & 31;
    const int ty = t >> 5;  // 0..15, rows ty*4..+3
    float acc[4][8];
#pragma unroll
    for (int i = 0; i < 4; i++)
#pragma unroll
      for (int j = 0; j < 8; j++) acc[i][j] = 0.0f;

    for (int kc = 0; kc < 100; kc += KC) {
      for (int i = t; i < BM * KC; i += 512) {
        int r = i / KC, k = i - r * KC;
        At[k * BMP + r] = h2[(rowBase + r) * 100 + kc + k];
      }
#pragma unroll
      for (int i = t; i < KC * 256; i += 512) {
        int k = i >> 8, c = i & 255;
        Ws[i] = (c < 200) ? wl[(kc + k) * 200 + c] : 0.0f;
      }
      __syncthreads();
#pragma unroll
      for (int k = 0; k < KC; k++) {
        float a[4], b[8];
        *(float4*)&a[0] = *(const float4*)&At[k * BMP + ty * 4];
        *(float4*)&b[0] = *(const float4*)&Ws[k * 256 + tx * 8];
        *(float4*)&b[4] = *(const float4*)&Ws[k * 256 + tx * 8 + 4];
#pragma unroll
        for (int i = 0; i < 4; i++)
#pragma unroll
          for (int j = 0; j < 8; j++) acc[i][j] += a[i] * b[j];
      }
      __syncthreads();  // all threads done reading At/Ws -> safe to overwrite with lg
    }

    if (tx < 25) {
#pragma unroll
      for (int i = 0; i < 4; i++) {
        const int r = ty * 4 + i;
        float4 v0, v1;
        v0.x = acc[i][0] + bl[tx * 8 + 0];
        v0.y = acc[i][1] + bl[tx * 8 + 1];
        v0.z = acc[i][2] + bl[tx * 8 + 2];
        v0.w = acc[i][3] + bl[tx * 8 + 3];
        v1.x = acc[i][4] + bl[tx * 8 + 4];
        v1.y = acc[i][5] + bl[tx * 8 + 5];
        v1.z = acc[i][6] + bl[tx * 8 + 6];
        v1.w = acc[i][7] + bl[tx * 8 + 7];
        *(float4*)&lg[r * 200 + tx * 8] = v0;
        *(float4*)&lg[r * 200 + tx * 8 + 4] = v1;
      }
    }
    __syncthreads();
  }

  // ---- Phase 2: SampleConcrete + head; one wave per row, 8 rows/wave ----
  const int lane = t & 63;
  const int wave = t >> 6;  // 0..7
  const size_t samplesBase = (size_t)B * 2;

#pragma unroll 1
  for (int rr = 0; rr < 8; rr++) {
    const int r = wave * 8 + rr;
    const int b = rowBase + r;
    const float* __restrict__ u = uniform + (size_t)b * 2000;

    float lgv[4], xv[4];
    bool vld[4];
#pragma unroll
    for (int i = 0; i < 4; i++) {
      const int d = lane + 64 * i;
      vld[i] = (d < 200);
      lgv[i] = vld[i] ? lg[r * 200 + d] : -1e30f;
      xv[i]  = vld[i] ? x[(size_t)b * 200 + d] : 0.0f;
    }

    // row max of logits (once per row — replaces the per-sample max reduce)
    float m = fmaxf(fmaxf(lgv[0], lgv[1]), fmaxf(lgv[2], lgv[3]));
#pragma unroll
    for (int off = 32; off > 0; off >>= 1) m = fmaxf(m, __shfl_xor(m, off, 64));

    // el_d = exp(2*(lg_d - lgmax)); invalid lanes contribute 0 to every sum
    float el[4];
#pragma unroll
    for (int i = 0; i < 4; i++) el[i] = vld[i] ? __expf(2.0f * (lgv[i] - m)) : 0.0f;

    float smax[4] = {0.0f, 0.0f, 0.0f, 0.0f};

    // 2-deep double buffer of uniform loads (invalid lanes -> 0.5: log2=-1, s=el*1=0)
    float uc[2][4];
#pragma unroll
    for (int i = 0; i < 4; i++) uc[0][i] = vld[i] ? u[lane + 64 * i] : 0.5f;

#pragma unroll
    for (int k = 0; k < 10; k++) {
      if (k < 9) {
#pragma unroll
        for (int i = 0; i < 4; i++)
          uc[(k + 1) & 1][i] = vld[i] ? u[(k + 1) * 200 + lane + 64 * i] : 0.5f;
      }
      float s[4], ssum = 0.0f;
#pragma unroll
      for (int i = 0; i < 4; i++) {
        const float q = __log2f(fmaxf(uc[k & 1][i], EPS));  // upper clip is a no-op: u in [0,1)
        s[i] = el[i] * __builtin_amdgcn_rcpf(q * q);
        ssum += s[i];
      }
#pragma unroll
      for (int off = 32; off > 0; off >>= 1) ssum += __shfl_xor(ssum, off, 64);
      const float inv = __builtin_amdgcn_rcpf(ssum);
#pragma unroll
      for (int i = 0; i < 4; i++) smax[i] = fmaxf(smax[i], s[i] * inv);
    }

    float p0 = 0.0f, p1 = 0.0f;
#pragma unroll
    for (int i = 0; i < 4; i++) {
      const int d = lane + 64 * i;
      if (d < 200) {
        const float s = smax[i];
        out[samplesBase + (size_t)b * 200 + d] = s;
        const float xs = xv[i] * s;
        p0 += xs * wo[d * 2 + 0];
        p1 += xs * wo[d * 2 + 1];
      }
    }
#pragma unroll
    for (int off = 32; off > 0; off >>= 1) {
      p0 += __shfl_xor(p0, off, 64);
      p1 += __shfl_xor(p1, off, 64);
    }
    if (lane == 0) {
      const float z0 = p0 + bo[0];
      const float z1 = p1 + bo[1];
      const float mh = fmaxf(z0, z1);
      const float e0 = __expf(z0 - mh);
      const float e1 = __expf(z1 - mh);
      out[b * 2 + 0] = e0 / (e0 + e1);
      out[b * 2 + 1] = e1 / (e0 + e1);
    }
  }
}

extern "C" void kernel_launch(void* const* d_in, const int* in_sizes, int n_in,
                              void* d_out, int out_size, void* d_ws, size_t ws_size,
                              hipStream_t stream) {
  const float* x  = (const float*)d_in[0];
  const float* un = (const float*)d_in[1];
  const float* w1 = (const float*)d_in[2];
  const float* b1 = (const float*)d_in[3];
  const float* w2 = (const float*)d_in[4];
  const float* b2 = (const float*)d_in[5];
  const float* wl = (const float*)d_in[6];
  const float* bl = (const float*)d_in[7];
  const float* wo = (const float*)d_in[8];
  const float* bo = (const float*)d_in[9];
  float* out = (float*)d_out;

  const int B = in_sizes[0] / 200;  // 32768
  float* h2 = (float*)d_ws;         // B*100 fp32 = 13.1 MB

  fused_mlp12<<<B / 64, 256, 0, stream>>>(x, w1, b1, w2, b2, h2);
  fused_logits_concrete<<<B / 64, 512, 0, stream>>>(x, un, h2, wl, bl, wo, bo, out, B);
}

// Round 2
// 534.615 us; speedup vs baseline: 1.0883x; 1.0883x over previous
//
#include <hip/hip_runtime.h>
#include <hip/hip_bf16.h>

// ---------------------------------------------------------------------------
// Kernel A: fused dense1+dense2.  h2 = relu(relu(x@w1+b1)@w2+b2)
// (unchanged — isolating kernel-B changes)
// ---------------------------------------------------------------------------
__launch_bounds__(256)
__global__ void fused_mlp12(const float* __restrict__ x,
                            const float* __restrict__ w1, const float* __restrict__ b1,
                            const float* __restrict__ w2, const float* __restrict__ b2,
                            float* __restrict__ h2out) {
  constexpr int BM = 64, KC = 20, BMP = 68;  // BMP*4B = 272B, 16B-aligned rows
  __shared__ float At[KC * BMP];    // 5.4 KB  staging: x^T chunk [k][r]
  __shared__ float Ws[KC * 128];    // 10.2 KB staging: weight chunk [k][c], cols padded
  __shared__ float h1T[100 * BMP];  // 27.2 KB h1 transposed [k][r]

  const int t = threadIdx.x;
  const int tx = t & 31;
  const int ty = t >> 5;
  const int rowBase = blockIdx.x * BM;

  float acc[8][4];
#pragma unroll
  for (int i = 0; i < 8; i++)
#pragma unroll
    for (int j = 0; j < 4; j++) acc[i][j] = 0.0f;

  // ---- GEMM 1: x(64x200) @ w1(200x100) ----
  for (int kc = 0; kc < 200; kc += KC) {
#pragma unroll
    for (int i = t; i < BM * KC; i += 256) {
      int r = i / KC, k = i - r * KC;
      At[k * BMP + r] = x[(rowBase + r) * 200 + kc + k];
    }
#pragma unroll
    for (int i = t; i < KC * 128; i += 256) {
      int k = i >> 7, c = i & 127;
      Ws[i] = (c < 100) ? w1[(kc + k) * 100 + c] : 0.0f;
    }
    __syncthreads();
#pragma unroll
    for (int k = 0; k < KC; k++) {
      float a[8], b[4];
      *(float4*)&a[0] = *(const float4*)&At[k * BMP + ty * 8];
      *(float4*)&a[4] = *(const float4*)&At[k * BMP + ty * 8 + 4];
      *(float4*)&b[0] = *(const float4*)&Ws[k * 128 + tx * 4];
#pragma unroll
      for (int i = 0; i < 8; i++)
#pragma unroll
        for (int j = 0; j < 4; j++) acc[i][j] += a[i] * b[j];
    }
    __syncthreads();
  }

  // h1 (bias+relu) -> LDS transposed [k][r]
  if (tx < 25) {
#pragma unroll
    for (int i = 0; i < 8; i++) {
      const int r = ty * 8 + i;
#pragma unroll
      for (int j = 0; j < 4; j++) {
        const int c = tx * 4 + j;
        h1T[c * BMP + r] = fmaxf(acc[i][j] + b1[c], 0.0f);
      }
    }
  }
  __syncthreads();

  // ---- GEMM 2: h1(64x100) @ w2(100x100) ----
#pragma unroll
  for (int i = 0; i < 8; i++)
#pragma unroll
    for (int j = 0; j < 4; j++) acc[i][j] = 0.0f;

  for (int kc = 0; kc < 100; kc += KC) {
#pragma unroll
    for (int i = t; i < KC * 128; i += 256) {
      int k = i >> 7, c = i & 127;
      Ws[i] = (c < 100) ? w2[(kc + k) * 100 + c] : 0.0f;
    }
    __syncthreads();
#pragma unroll
    for (int k = 0; k < KC; k++) {
      float a[8], b[4];
      *(float4*)&a[0] = *(const float4*)&h1T[(kc + k) * BMP + ty * 8];
      *(float4*)&a[4] = *(const float4*)&h1T[(kc + k) * BMP + ty * 8 + 4];
      *(float4*)&b[0] = *(const float4*)&Ws[k * 128 + tx * 4];
#pragma unroll
      for (int i = 0; i < 8; i++)
#pragma unroll
        for (int j = 0; j < 4; j++) acc[i][j] += a[i] * b[j];
    }
    __syncthreads();
  }

  if (tx < 25) {
#pragma unroll
    for (int i = 0; i < 8; i++) {
      const int r = rowBase + ty * 8 + i;
      float4 v;
      v.x = fmaxf(acc[i][0] + b2[tx * 4 + 0], 0.0f);
      v.y = fmaxf(acc[i][1] + b2[tx * 4 + 1], 0.0f);
      v.z = fmaxf(acc[i][2] + b2[tx * 4 + 2], 0.0f);
      v.w = fmaxf(acc[i][3] + b2[tx * 4 + 3], 0.0f);
      *(float4*)&h2out[r * 100 + tx * 4] = v;
    }
  }
}

// ---------------------------------------------------------------------------
// Kernel B: fused logits-GEMM + SampleConcrete + head.
// Round-2 changes (post-mortem of round 1: factorized math halved VALUBusy
// 63->24% but dur rose 192->208us — latency-exposed; occupancy is GRID-capped
// at 2 blocks/CU (512 blocks), so the LDS cut bought nothing):
//  1) Restore round-0's 40-deep load batch: all 10 samples' uniforms loaded
//     into s[10][4] up front (40 global loads in flight), THEN transformed.
//  2) Keep the factorized math: s_kd = el_d / log2(u_kd)^2, el_d computed
//     once per row, no per-sample max-reduce (validated: round 1 passed).
//  3) The ten 64-lane sum-reductions run as 10 INDEPENDENT interleaved
//     butterfly chains (all s computed first) — shuffle latency pipelines
//     across k instead of serializing 10 x 6 dependent steps.
//  4) Samples output via __builtin_nontemporal_store: write-once 25MB stream
//     stops evicting the 262MB uniform stream from L3 (round-1 FETCH/WRITE
//     blew up +55MB each).
//  __launch_bounds__(512,4): VGPR cap 128 (need ~90 for the 40-reg batch).
// ---------------------------------------------------------------------------
__launch_bounds__(512, 4)
__global__ void fused_logits_concrete(const float* __restrict__ x,
                                      const float* __restrict__ uniform,
                                      const float* __restrict__ h2,
                                      const float* __restrict__ wl, const float* __restrict__ bl,
                                      const float* __restrict__ wo, const float* __restrict__ bo,
                                      float* __restrict__ out, int B) {
  constexpr int BM = 64, KC = 20, BMP = 68;
  constexpr float EPS = 1.1920929e-07f;
  // 51.2 KB total: staging (At 1360 + Ws 5120 floats) aliases lg[12800].
  __shared__ float smem[BM * 200];
  float* const At = smem;             // [KC][BMP]   (phase 1 only)
  float* const Ws = smem + KC * BMP;  // [KC][256]   (phase 1 only)
  float* const lg = smem;             // [BM][200]   (written after last GEMM sync)

  const int t = threadIdx.x;
  const int rowBase = blockIdx.x * BM;

  // ---- Phase 1: logits = h2(64x100) @ wl(100x200) + bl ----
  {
    const int tx = t & 31;
    const int ty = t >> 5;  // 0..15, rows ty*4..+3
    float acc[4][8];
#pragma unroll
    for (int i = 0; i < 4; i++)
#pragma unroll
      for (int j = 0; j < 8; j++) acc[i][j] = 0.0f;

    for (int kc = 0; kc < 100; kc += KC) {
      for (int i = t; i < BM * KC; i += 512) {
        int r = i / KC, k = i - r * KC;
        At[k * BMP + r] = h2[(rowBase + r) * 100 + kc + k];
      }
#pragma unroll
      for (int i = t; i < KC * 256; i += 512) {
        int k = i >> 8, c = i & 255;
        Ws[i] = (c < 200) ? wl[(kc + k) * 200 + c] : 0.0f;
      }
      __syncthreads();
#pragma unroll
      for (int k = 0; k < KC; k++) {
        float a[4], b[8];
        *(float4*)&a[0] = *(const float4*)&At[k * BMP + ty * 4];
        *(float4*)&b[0] = *(const float4*)&Ws[k * 256 + tx * 8];
        *(float4*)&b[4] = *(const float4*)&Ws[k * 256 + tx * 8 + 4];
#pragma unroll
        for (int i = 0; i < 4; i++)
#pragma unroll
          for (int j = 0; j < 8; j++) acc[i][j] += a[i] * b[j];
      }
      __syncthreads();  // all reads of At/Ws done -> safe to overwrite with lg
    }

    if (tx < 25) {
#pragma unroll
      for (int i = 0; i < 4; i++) {
        const int r = ty * 4 + i;
        float4 v0, v1;
        v0.x = acc[i][0] + bl[tx * 8 + 0];
        v0.y = acc[i][1] + bl[tx * 8 + 1];
        v0.z = acc[i][2] + bl[tx * 8 + 2];
        v0.w = acc[i][3] + bl[tx * 8 + 3];
        v1.x = acc[i][4] + bl[tx * 8 + 4];
        v1.y = acc[i][5] + bl[tx * 8 + 5];
        v1.z = acc[i][6] + bl[tx * 8 + 6];
        v1.w = acc[i][7] + bl[tx * 8 + 7];
        *(float4*)&lg[r * 200 + tx * 8] = v0;
        *(float4*)&lg[r * 200 + tx * 8 + 4] = v1;
      }
    }
    __syncthreads();
  }

  // ---- Phase 2: SampleConcrete + head; one wave per row, 8 rows/wave ----
  const int lane = t & 63;
  const int wave = t >> 6;  // 0..7
  const size_t samplesBase = (size_t)B * 2;

#pragma unroll 1
  for (int rr = 0; rr < 8; rr++) {
    const int r = wave * 8 + rr;
    const int b = rowBase + r;
    const float* __restrict__ u = uniform + (size_t)b * 2000;

    float lgv[4], xv[4];
    bool vld[4];
#pragma unroll
    for (int i = 0; i < 4; i++) {
      const int d = lane + 64 * i;
      vld[i] = (d < 200);
      lgv[i] = vld[i] ? lg[r * 200 + d] : -1e30f;
      xv[i]  = vld[i] ? x[(size_t)b * 200 + d] : 0.0f;
    }

    // Batch ALL 10 samples' uniforms first: 40 loads in flight per lane.
    float s[10][4];
#pragma unroll
    for (int k = 0; k < 10; k++)
#pragma unroll
      for (int i = 0; i < 4; i++)
        s[k][i] = vld[i] ? u[k * 200 + lane + 64 * i] : 0.5f;

    // Row max of logits (once per row)
    float m = fmaxf(fmaxf(lgv[0], lgv[1]), fmaxf(lgv[2], lgv[3]));
#pragma unroll
    for (int off = 32; off > 0; off >>= 1) m = fmaxf(m, __shfl_xor(m, off, 64));

    // el_d = exp(2*(lg_d - lgmax)); invalid lanes -> 0 (never pollute sums)
    float el[4];
#pragma unroll
    for (int i = 0; i < 4; i++) el[i] = vld[i] ? __expf(2.0f * (lgv[i] - m)) : 0.0f;

    // In-place transform: s = el / log2(u)^2  (ln^2(2) cancels in softmax;
    // invalid lanes: u=0.5 -> q=-1 -> rcp(1)=1, times el=0 -> 0).
    // All 80 transcendentals independent -> trans pipe stays full.
#pragma unroll
    for (int k = 0; k < 10; k++)
#pragma unroll
      for (int i = 0; i < 4; i++) {
        const float q = __log2f(fmaxf(s[k][i], EPS));
        s[k][i] = el[i] * __builtin_amdgcn_rcpf(q * q);
      }

    // 10 independent butterfly reductions, interleaved (pipelined shuffles)
    float ps[10];
#pragma unroll
    for (int k = 0; k < 10; k++) ps[k] = (s[k][0] + s[k][1]) + (s[k][2] + s[k][3]);
#pragma unroll
    for (int off = 32; off > 0; off >>= 1)
#pragma unroll
      for (int k = 0; k < 10; k++) ps[k] += __shfl_xor(ps[k], off, 64);
#pragma unroll
    for (int k = 0; k < 10; k++) ps[k] = __builtin_amdgcn_rcpf(ps[k]);

    float smax[4] = {0.0f, 0.0f, 0.0f, 0.0f};
#pragma unroll
    for (int k = 0; k < 10; k++)
#pragma unroll
      for (int i = 0; i < 4; i++) smax[i] = fmaxf(smax[i], s[k][i] * ps[k]);

    float p0 = 0.0f, p1 = 0.0f;
#pragma unroll
    for (int i = 0; i < 4; i++) {
      const int d = lane + 64 * i;
      if (d < 200) {
        const float sv = smax[i];
        __builtin_nontemporal_store(sv, &out[samplesBase + (size_t)b * 200 + d]);
        const float xs = xv[i] * sv;
        p0 += xs * wo[d * 2 + 0];
        p1 += xs * wo[d * 2 + 1];
      }
    }
#pragma unroll
    for (int off = 32; off > 0; off >>= 1) {
      p0 += __shfl_xor(p0, off, 64);
      p1 += __shfl_xor(p1, off, 64);
    }
    if (lane == 0) {
      const float z0 = p0 + bo[0];
      const float z1 = p1 + bo[1];
      const float mh = fmaxf(z0, z1);
      const float e0 = __expf(z0 - mh);
      const float e1 = __expf(z1 - mh);
      out[b * 2 + 0] = e0 / (e0 + e1);
      out[b * 2 + 1] = e1 / (e0 + e1);
    }
  }
}

extern "C" void kernel_launch(void* const* d_in, const int* in_sizes, int n_in,
                              void* d_out, int out_size, void* d_ws, size_t ws_size,
                              hipStream_t stream) {
  const float* x  = (const float*)d_in[0];
  const float* un = (const float*)d_in[1];
  const float* w1 = (const float*)d_in[2];
  const float* b1 = (const float*)d_in[3];
  const float* w2 = (const float*)d_in[4];
  const float* b2 = (const float*)d_in[5];
  const float* wl = (const float*)d_in[6];
  const float* bl = (const float*)d_in[7];
  const float* wo = (const float*)d_in[8];
  const float* bo = (const float*)d_in[9];
  float* out = (float*)d_out;

  const int B = in_sizes[0] / 200;  // 32768
  float* h2 = (float*)d_ws;         // B*100 fp32 = 13.1 MB

  fused_mlp12<<<B / 64, 256, 0, stream>>>(x, w1, b1, w2, b2, h2);
  fused_logits_concrete<<<B / 64, 512, 0, stream>>>(x, un, h2, wl, bl, wo, bo, out, B);
}